// Round 12
// baseline (88.686 us; speedup 1.0000x reference)
//
#include <hip/hip_runtime.h>

typedef unsigned int uint32;
typedef unsigned short ushort;
typedef __attribute__((ext_vector_type(8))) short short8;   // 8 bf16 = 4 VGPR
typedef __attribute__((ext_vector_type(4))) float f32x4;

#define NNODES 32768
#define NGRAPH 128
#define PNODES 256
#define SQ 32
#define NEDGE 524288
#define DIM 128
#define NHEAD 4
#define MAXDEG 64     // slots per node (mean 16, ~12 sigma headroom)

__device__ __forceinline__ float u2f(uint32 u){ union{uint32 i; float f;} c; c.i=u; return c.f; }
__device__ __forceinline__ uint32 f2bf(float f){
  union{float f; uint32 i;} c; c.f=f;
  return (c.i + 0x7FFFu + ((c.i>>16)&1u)) >> 16;
}
__device__ __forceinline__ uint32 pk2(float a, float b){ return f2bf(a) | (f2bf(b)<<16); }

// ---------------- weight prep (blocks 0-3) + zero deg (blocks 4-35) ----------------
__global__ __launch_bounds__(256) void k_prep0(const float* __restrict__ Wk,
    const float* __restrict__ Wv, const float* __restrict__ Wq, const float* __restrict__ Wo,
    ushort* __restrict__ WTk, ushort* __restrict__ WTv, ushort* __restrict__ WTq,
    ushort* __restrict__ WTo, int4* __restrict__ zbase){
  const int bid = blockIdx.x;
  const int t = threadIdx.x;
  if (bid >= 4){
    int idx = (bid-4)*256 + t;
    if (idx < 8192) zbase[idx] = int4{0,0,0,0};   // deg[32768]
    return;
  }
  __shared__ __align__(16) float Ws2[128*132];
  const float* W = (bid==0) ? Wk : (bid==1) ? Wv : (bid==2) ? Wq : Wo;
  ushort* WT     = (bid==0) ? WTk : (bid==1) ? WTv : (bid==2) ? WTq : WTo;
  for (int idx = t; idx < 4096; idx += 256){
    int k = idx >> 5, c4 = idx & 31;
    *(float4*)&Ws2[k*132 + c4*4] = *(const float4*)&W[k*128 + c4*4];
  }
  __syncthreads();
  for (int idx = t; idx < 2048; idx += 256){
    int n = idx & 127, c8 = idx >> 7;
    uint4 p;
    p.x = pk2(Ws2[(c8*8+0)*132 + n], Ws2[(c8*8+1)*132 + n]);
    p.y = pk2(Ws2[(c8*8+2)*132 + n], Ws2[(c8*8+3)*132 + n]);
    p.z = pk2(Ws2[(c8*8+4)*132 + n], Ws2[(c8*8+5)*132 + n]);
    p.w = pk2(Ws2[(c8*8+6)*132 + n], Ws2[(c8*8+7)*132 + n]);
    *(uint4*)&WT[n*128 + c8*8] = p;
  }
}

// ---------------- edges: deg atomicAdd doubles as slot allocator ----------------
__global__ void k_edges(const int* __restrict__ ei, int* __restrict__ deg,
                        ushort* __restrict__ ebuf){
  int e = blockIdx.x*256 + threadIdx.x;        // grid exact: NEDGE/256
  int s = ei[e];
  int d = ei[NEDGE + e];
  int i = atomicAdd(&deg[d], 1);               // 32768 counters: low contention
  if (i < MAXDEG) ebuf[(d << 6) + i] = (ushort)(s & 255);
}

// ---------------- fused aggregation + K/V GEMM per half-graph ----------------
// K written natural [node][d]; V written TRANSPOSED [graph][d][p] for attnepi.
#define APITCH 132   // u32 per A row (= 264 ushort)
__global__ __launch_bounds__(512) void k_aggkv(
    const int* __restrict__ deg, const ushort* __restrict__ ebuf,
    const float* __restrict__ x,
    const ushort* __restrict__ WTk, const float* __restrict__ bk, ushort* __restrict__ Kb,
    const ushort* __restrict__ WTv, const float* __restrict__ bv, ushort* __restrict__ VbT)
{
  __shared__ __align__(16) char lds[138240];
  uint32* A    = (uint32*)lds;             // [128][132] u32 = bf16 pairs [dst][src]
  ushort* Au   = (ushort*)lds;             // bf16 view
  ushort* xT   = (ushort*)(lds + 67584);   // [128 feat][264 src] bf16
  ushort* xa_s = (ushort*)(lds + 67584);   // [128][136] bf16 (overlays xT after agg)
  ushort* wtA  = (ushort*)(lds + 102400);  // [128][136] bf16 (Wk^T)
  ushort* wtB  = (ushort*)(lds + 0);       // [128][136] bf16 (Wv^T; overlays A)
  ushort* KK   = (ushort*)(lds + 67584);   // K bounce [row][136] (overlays xa_s)
  ushort* VVt  = (ushort*)(lds + 102400);  // V bounce TRANSPOSED [d][136] (overlays wtA)
  float*  dvs  = (float*)(lds + 137216);   // [256]
  const int t = threadIdx.x;
  const int g = blockIdx.x >> 1, half = blockIdx.x & 1;
  const int base = g*PNODES;
  const int rbase = half*128;

  // Prefetch both weight matrices into registers (drained at P4, ~3 phases away)
  uint4 wAr[4], wBr[4];
  #pragma unroll
  for (int i = 0; i < 4; ++i){
    const int idx = t + i*512;
    const int n = idx >> 4, c8 = idx & 15;
    wAr[i] = *(const uint4*)&WTk[n*128 + c8*8];
    wBr[i] = *(const uint4*)&WTv[n*128 + c8*8];
  }

  // P0: dinv + zero A + stage x^T (independent; x loads overlap A-zero)
  if (t < 256) dvs[t] = rsqrtf((float)(deg[base + t] + 1));
  {
    uint4* Az = (uint4*)A;
    for (int i = t; i < 4224; i += 512) Az[i] = uint4{0,0,0,0};
  }
  for (int idx = t; idx < 8192; idx += 512){
    int f = idx & 127, s4 = idx >> 7;
    const int r = base + s4*4;
    float v0 = x[(r+0)*DIM + f];
    float v1 = x[(r+1)*DIM + f];
    float v2 = x[(r+2)*DIM + f];
    float v3 = x[(r+3)*DIM + f];
    uint2 p; p.x = pk2(v0, v1); p.y = pk2(v2, v3);
    *(uint2*)&xT[f*264 + s4*4] = p;
  }
  __syncthreads();
  // P1: diagonal (self-loop dn^2) + edge accumulation (cell-ownership, no atomics)
  if (t < 128){
    float dn = dvs[rbase + t];
    int src = rbase + t;
    uint32 nb = f2bf(dn*dn);
    uint32 old = A[t*APITCH + (src>>1)];
    A[t*APITCH + (src>>1)] = (src & 1) ? ((old & 0xffffu) | (nb<<16))
                                       : ((old & 0xffff0000u) | nb);
  }
  {
    const int r = t >> 2, sub = t & 3;
    const int n = base + rbase + r;
    const int dg = min(deg[n], MAXDEG);
    const float dn = dvs[rbase + r];
    const ushort* eb = ebuf + (n << 6);
    for (int i = 0; i < dg; ++i){
      const int srcl = eb[i];
      if (((srcl >> 1) & 3) != sub) continue;
      const float coef = dn * dvs[srcl];
      uint32* cell = &A[r*APITCH + (srcl>>1)];
      uint32 old = *cell;
      if (srcl & 1){
        float cur = u2f(old & 0xffff0000u);
        *cell = (old & 0xffffu) | (f2bf(cur + coef) << 16);
      } else {
        float cur = u2f(old << 16);
        *cell = (old & 0xffff0000u) | f2bf(cur + coef);
      }
    }
  }
  __syncthreads();
  // P3: xa = A @ x
  const int lane = t & 63, w = t >> 6;
  const int r16 = lane & 15, kg = lane >> 4;
  f32x4 acc[8];
  #pragma unroll
  for (int j = 0; j < 8; ++j) acc[j] = (f32x4){0.f,0.f,0.f,0.f};
  #pragma unroll
  for (int kc = 0; kc < 8; ++kc){
    const short8 a = *(const short8*)&Au[(w*16 + r16)*264 + kc*32 + kg*8];
    #pragma unroll
    for (int ct = 0; ct < 8; ++ct){
      const short8 b = *(const short8*)&xT[(ct*16 + r16)*264 + kc*32 + kg*8];
      acc[ct] = __builtin_amdgcn_mfma_f32_16x16x32_bf16(a, b, acc[ct], 0, 0, 0);
    }
  }
  __syncthreads();
  // P4: xa -> LDS bf16 + drain prefetched weights into LDS
  #pragma unroll
  for (int ct = 0; ct < 8; ++ct)
    #pragma unroll
    for (int q = 0; q < 4; ++q)
      xa_s[(w*16 + kg*4 + q)*136 + ct*16 + r16] = (ushort)f2bf(acc[ct][q]);
  #pragma unroll
  for (int i = 0; i < 4; ++i){
    const int idx = t + i*512;
    const int n = idx >> 4, c8 = idx & 15;
    *(uint4*)&wtA[n*136 + c8*8] = wAr[i];
    *(uint4*)&wtB[n*136 + c8*8] = wBr[i];
  }
  __syncthreads();
  // P5: K = xa@Wk + bk ; V = xa@Wv + bv
  f32x4 k0[8], v0[8];
  #pragma unroll
  for (int j = 0; j < 8; ++j){ k0[j] = (f32x4){0.f,0.f,0.f,0.f}; v0[j] = (f32x4){0.f,0.f,0.f,0.f}; }
  #pragma unroll
  for (int kc = 0; kc < 4; ++kc){
    const short8 a = *(const short8*)&xa_s[(w*16 + r16)*136 + kc*32 + kg*8];
    #pragma unroll
    for (int ct = 0; ct < 8; ++ct){
      const short8 b0 = *(const short8*)&wtA[(ct*16 + r16)*136 + kc*32 + kg*8];
      const short8 b1 = *(const short8*)&wtB[(ct*16 + r16)*136 + kc*32 + kg*8];
      k0[ct] = __builtin_amdgcn_mfma_f32_16x16x32_bf16(a, b0, k0[ct], 0, 0, 0);
      v0[ct] = __builtin_amdgcn_mfma_f32_16x16x32_bf16(a, b1, v0[ct], 0, 0, 0);
    }
  }
  __syncthreads();   // all waves done reading xa_s / wtA before bounce overwrite
  #pragma unroll
  for (int ct = 0; ct < 8; ++ct){
    const int col = ct*16 + r16;
    const float bkc = bk[col], bvc = bv[col];
    #pragma unroll
    for (int q = 0; q < 4; ++q){
      const int r = w*16 + kg*4 + q;                 // local row = p
      KK[r*136 + col]  = (ushort)f2bf(k0[ct][q] + bkc);
      VVt[col*136 + r] = (ushort)f2bf(v0[ct][q] + bvc);   // transposed bounce
    }
  }
  __syncthreads();
  // P6: coalesced uint4 stores: K natural, V transposed [g][d][p]
  for (int idx = t; idx < 2048; idx += 512){
    int r = idx >> 4, c8 = idx & 15;
    *(uint4*)&Kb[(base + rbase + r)*DIM + c8*8] = *(const uint4*)&KK[r*136 + c8*8];
  }
  for (int idx = t; idx < 2048; idx += 512){
    int d = idx >> 4, c8 = idx & 15;                 // p-chunk c8*8 within half
    *(uint4*)&VbT[(g*128 + d)*PNODES + rbase + c8*8] = *(const uint4*)&VVt[d*136 + c8*8];
  }
}

// ---------------- fused Q-GEMM + MFMA attention + epilogue (async-prefetched) ----
// 2 blocks/graph (16 queries), 512 threads = 8 waves. T14 issue-early/write-late:
// WqT drained immediately, K drained during Q-GEMM, V^T during softmax, WoT in LN0.
__global__ __launch_bounds__(512) void k_attnepi(
    const float* __restrict__ Qin, const ushort* __restrict__ WTq,
    const float* __restrict__ bq,
    const ushort* __restrict__ Kb, const ushort* __restrict__ VbT,
    const ushort* __restrict__ WoT, const float* __restrict__ bo,
    const float* __restrict__ g0, const float* __restrict__ b0,
    const float* __restrict__ g1, const float* __restrict__ b1,
    float* __restrict__ out)
{
  __shared__ __align__(16) char lds[151040];
  ushort* KbS = (ushort*)lds;             // [256][136] bf16 (69632 B)
  ushort* VT  = (ushort*)lds;             // [128][264] bf16 (67584 B) overlays KbS
  ushort* R2  = (ushort*)(lds + 69632);   // [128][136] bf16: WqT then WoT (34816 B)
  float*  S   = (float*)(lds + 104448);   // [16][264] f32 (16896 B)
  float*  Zf  = (float*)(lds + 104448);   // overlays S
  ushort* Pb  = (ushort*)(lds + 121344);  // [16][264] bf16 (8448 B)
  float*  Yf  = (float*)(lds + 121344);   // [16][132] f32 overlays Pb
  float*  Ob  = (float*)(lds + 129792);   // [16][132] f32 (8448 B)
  float*  Qres= (float*)(lds + 138240);   // [16][132] f32 (8448 B)
  ushort* Qb  = (ushort*)(lds + 146688);  // [16][136] bf16 (4352 B), reused as Yb

  const int t = threadIdx.x;
  const int w = t >> 6, lane = t & 63;
  const int r16 = lane & 15, kg = lane >> 4;
  const int g = blockIdx.x >> 1, qh = blockIdx.x & 1;
  const int qr0 = g*SQ + qh*16;

  // Issue order matters (vmcnt retires in order): WqT -> Q -> K -> V^T.
  uint4 wq[4];
  #pragma unroll
  for (int i = 0; i < 4; ++i){
    const int idx = t + i*512;
    wq[i] = *(const uint4*)&WTq[(idx >> 4)*128 + (idx & 15)*8];
  }
  float4 qf0[4], qf1[4];
  #pragma unroll
  for (int kc = 0; kc < 4; ++kc){
    qf0[kc] = *(const float4*)&Qin[(qr0 + r16)*128 + kc*32 + kg*8];
    qf1[kc] = *(const float4*)&Qin[(qr0 + r16)*128 + kc*32 + kg*8 + 4];
  }
  uint4 kr[8];
  #pragma unroll
  for (int i = 0; i < 8; ++i){
    const int idx = t + i*512;
    kr[i] = *(const uint4*)&Kb[(g*256 + (idx >> 4))*128 + (idx & 15)*8];
  }
  uint4 vr[8];
  #pragma unroll
  for (int i = 0; i < 8; ++i){
    const int idx = t + i*512;
    vr[i] = *(const uint4*)&VbT[(g*128 + (idx >> 5))*PNODES + (idx & 31)*8];
  }

  // A: drain WqT -> R2 ; pack Q fragments (K, V^T still in flight)
  #pragma unroll
  for (int i = 0; i < 4; ++i){
    const int idx = t + i*512;
    *(uint4*)&R2[(idx >> 4)*136 + (idx & 15)*8] = wq[i];
  }
  short8 qin[4];
  #pragma unroll
  for (int kc = 0; kc < 4; ++kc){
    union { short8 s; uint32 u[4]; } c;
    c.u[0] = pk2(qf0[kc].x, qf0[kc].y); c.u[1] = pk2(qf0[kc].z, qf0[kc].w);
    c.u[2] = pk2(qf1[kc].x, qf1[kc].y); c.u[3] = pk2(qf1[kc].z, qf1[kc].w);
    qin[kc] = c.s;
  }
  __syncthreads();

  // A2: Qp tile = Q @ Wq + bq ; drain K -> KbS under the MFMAs
  {
    f32x4 qa = (f32x4){0.f,0.f,0.f,0.f};
    #pragma unroll
    for (int kc = 0; kc < 4; ++kc){
      const short8 bf = *(const short8*)&R2[(w*16 + r16)*136 + kc*32 + kg*8];
      qa = __builtin_amdgcn_mfma_f32_16x16x32_bf16(qin[kc], bf, qa, 0, 0, 0);
    }
    #pragma unroll
    for (int i = 0; i < 8; ++i){
      const int idx = t + i*512;
      *(uint4*)&KbS[(idx >> 4)*136 + (idx & 15)*8] = kr[i];
    }
    #pragma unroll
    for (int q = 0; q < 4; ++q){
      const int row = kg*4 + q, col = w*16 + r16;
      const float v = qa[q] + bq[col];
      Qres[row*132 + col] = v;
      Qb[row*136 + col] = (ushort)f2bf(v);
    }
  }
  __syncthreads();

  // B: scores S = (Qp·K^T)/sqrt(128); wave w owns key tiles {2w, 2w+1}
  {
    short8 qfr[4];
    #pragma unroll
    for (int kc = 0; kc < 4; ++kc)
      qfr[kc] = *(const short8*)&Qb[r16*136 + kc*32 + kg*8];
    f32x4 sa[2];
    sa[0] = (f32x4){0.f,0.f,0.f,0.f}; sa[1] = (f32x4){0.f,0.f,0.f,0.f};
    #pragma unroll
    for (int kc = 0; kc < 4; ++kc){
      #pragma unroll
      for (int nt = 0; nt < 2; ++nt){
        const short8 bf = *(const short8*)&KbS[((w*2+nt)*16 + r16)*136 + kc*32 + kg*8];
        sa[nt] = __builtin_amdgcn_mfma_f32_16x16x32_bf16(qfr[kc], bf, sa[nt], 0, 0, 0);
      }
    }
    #pragma unroll
    for (int nt = 0; nt < 2; ++nt)
      #pragma unroll
      for (int q = 0; q < 4; ++q)
        S[(kg*4+q)*264 + (w*2+nt)*16 + r16] = sa[nt][q] * 0.08838834764831845f;
  }
  __syncthreads();

  // C: softmax (32 thr/row) -> Pb bf16 ; drain V^T -> VT ; issue WoT prefetch
  uint4 wo[4];
  #pragma unroll
  for (int i = 0; i < 4; ++i){
    const int idx = t + i*512;
    wo[i] = *(const uint4*)&WoT[(idx >> 4)*128 + (idx & 15)*8];
  }
  {
    const int row = t >> 5, j = t & 31;
    float vals[8];
    float m = -1e30f;
    #pragma unroll
    for (int u = 0; u < 8; ++u){
      vals[u] = S[row*264 + j + 32*u];
      m = fmaxf(m, vals[u]);
    }
    m = fmaxf(m, __shfl_xor(m, 1));
    m = fmaxf(m, __shfl_xor(m, 2));
    m = fmaxf(m, __shfl_xor(m, 4));
    m = fmaxf(m, __shfl_xor(m, 8));
    m = fmaxf(m, __shfl_xor(m, 16));
    float sum = 0.f;
    #pragma unroll
    for (int u = 0; u < 8; ++u){
      vals[u] = __expf(vals[u] - m);
      sum += vals[u];
    }
    sum += __shfl_xor(sum, 1);
    sum += __shfl_xor(sum, 2);
    sum += __shfl_xor(sum, 4);
    sum += __shfl_xor(sum, 8);
    sum += __shfl_xor(sum, 16);
    float inv = 1.f / sum;
    #pragma unroll
    for (int u = 0; u < 8; ++u)
      Pb[row*264 + j + 32*u] = (ushort)f2bf(vals[u] * inv);
  }
  #pragma unroll
  for (int i = 0; i < 8; ++i){
    const int idx = t + i*512;
    *(uint4*)&VT[(idx >> 5)*264 + (idx & 31)*8] = vr[i];
  }
  __syncthreads();

  // D: O = P·V + Qp residual ; wave w owns d-tile w
  {
    f32x4 oa = (f32x4){0.f,0.f,0.f,0.f};
    #pragma unroll
    for (int kc = 0; kc < 8; ++kc){
      const short8 pa = *(const short8*)&Pb[r16*264 + kc*32 + kg*8];
      const short8 vb = *(const short8*)&VT[(w*16 + r16)*264 + kc*32 + kg*8];
      oa = __builtin_amdgcn_mfma_f32_16x16x32_bf16(pa, vb, oa, 0, 0, 0);
    }
    #pragma unroll
    for (int q = 0; q < 4; ++q){
      const int row = kg*4 + q, col = w*16 + r16;
      Ob[row*132 + col] = oa[q] + Qres[row*132 + col];
    }
  }
  __syncthreads();

  // E: LN0 -> Yf (f32) + Yb (bf16, reuses Qb slot) ; drain WoT -> R2
  #pragma unroll
  for (int rr = 0; rr < 2; ++rr){
    const int row = w*2 + rr;
    float x0 = Ob[row*132 + 2*lane], x1 = Ob[row*132 + 2*lane + 1];
    float s = x0 + x1;
    s += __shfl_xor(s,1); s += __shfl_xor(s,2); s += __shfl_xor(s,4);
    s += __shfl_xor(s,8); s += __shfl_xor(s,16); s += __shfl_xor(s,32);
    float mu = s * 0.0078125f;
    float d0 = x0 - mu, d1 = x1 - mu;
    float vv = d0*d0 + d1*d1;
    vv += __shfl_xor(vv,1); vv += __shfl_xor(vv,2); vv += __shfl_xor(vv,4);
    vv += __shfl_xor(vv,8); vv += __shfl_xor(vv,16); vv += __shfl_xor(vv,32);
    float rs = rsqrtf(vv*0.0078125f + 1e-5f);
    const float2 gv = *(const float2*)&g0[2*lane];
    const float2 bv = *(const float2*)&b0[2*lane];
    float y0 = d0*rs*gv.x + bv.x;
    float y1 = d1*rs*gv.y + bv.y;
    Yf[row*132 + 2*lane] = y0; Yf[row*132 + 2*lane + 1] = y1;
    *(uint32*)&Qb[row*136 + 2*lane] = pk2(y0, y1);
  }
  #pragma unroll
  for (int i = 0; i < 4; ++i){
    const int idx = t + i*512;
    *(uint4*)&R2[(idx >> 4)*136 + (idx & 15)*8] = wo[i];
  }
  __syncthreads();

  // F: Z = Y + relu(Y·Wo + bo) via MFMA ; wave w owns out-col tile w
  {
    f32x4 fa = (f32x4){0.f,0.f,0.f,0.f};
    #pragma unroll
    for (int kc = 0; kc < 4; ++kc){
      const short8 ya = *(const short8*)&Qb[r16*136 + kc*32 + kg*8];
      const short8 wb = *(const short8*)&R2[(w*16 + r16)*136 + kc*32 + kg*8];
      fa = __builtin_amdgcn_mfma_f32_16x16x32_bf16(ya, wb, fa, 0, 0, 0);
    }
    #pragma unroll
    for (int q = 0; q < 4; ++q){
      const int row = kg*4 + q, col = w*16 + r16;
      Zf[row*132 + col] = Yf[row*132 + col] + fmaxf(fa[q] + bo[col], 0.f);
    }
  }
  __syncthreads();

  // G: LN1 -> out
  #pragma unroll
  for (int rr = 0; rr < 2; ++rr){
    const int row = w*2 + rr;
    float z0 = Zf[row*132 + 2*lane], z1 = Zf[row*132 + 2*lane + 1];
    float s = z0 + z1;
    s += __shfl_xor(s,1); s += __shfl_xor(s,2); s += __shfl_xor(s,4);
    s += __shfl_xor(s,8); s += __shfl_xor(s,16); s += __shfl_xor(s,32);
    float mu = s * 0.0078125f;
    float d0 = z0 - mu, d1 = z1 - mu;
    float vv = d0*d0 + d1*d1;
    vv += __shfl_xor(vv,1); vv += __shfl_xor(vv,2); vv += __shfl_xor(vv,4);
    vv += __shfl_xor(vv,8); vv += __shfl_xor(vv,16); vv += __shfl_xor(vv,32);
    float rs = rsqrtf(vv*0.0078125f + 1e-5f);
    const float2 g1v = *(const float2*)&g1[2*lane];
    const float2 b1v = *(const float2*)&b1[2*lane];
    float2 o;
    o.x = d0*rs*g1v.x + b1v.x;
    o.y = d1*rs*g1v.y + b1v.y;
    *(float2*)&out[(qr0 + row)*128 + 2*lane] = o;
  }
}

extern "C" void kernel_launch(void* const* d_in, const int* in_sizes, int n_in,
                              void* d_out, int out_size, void* d_ws, size_t ws_size,
                              hipStream_t stream){
  const float* Q   = (const float*)d_in[0];
  const float* x   = (const float*)d_in[1];
  const int*   ei  = (const int*)d_in[2];
  const float* Wq  = (const float*)d_in[4];
  const float* bq  = (const float*)d_in[5];
  const float* Wk  = (const float*)d_in[6];
  const float* bk  = (const float*)d_in[7];
  const float* Wv  = (const float*)d_in[8];
  const float* bv  = (const float*)d_in[9];
  const float* Wo  = (const float*)d_in[10];
  const float* bo  = (const float*)d_in[11];
  const float* g0  = (const float*)d_in[12];
  const float* b0  = (const float*)d_in[13];
  const float* g1  = (const float*)d_in[14];
  const float* b1  = (const float*)d_in[15];

  char* ws = (char*)d_ws;
  ushort* Kb   = (ushort*)(ws);                  // 8 MB
  ushort* VbT  = (ushort*)(ws + 8388608);        // 8 MB  [g][d][p] transposed V
  ushort* WTk  = (ushort*)(ws + 16777216);       // 32 KB
  ushort* WTv  = (ushort*)(ws + 16809984);       // 32 KB
  ushort* WTq  = (ushort*)(ws + 16842752);       // 32 KB
  ushort* WTo  = (ushort*)(ws + 16875520);       // 32 KB
  int*    deg  = (int*)(ws + 16908288);          // 128 KB
  ushort* ebuf = (ushort*)(ws + 17039360);       // 32768*64*2 = 4 MB

  k_prep0<<<36, 256, 0, stream>>>(Wk, Wv, Wq, Wo, WTk, WTv, WTq, WTo, (int4*)deg);
  k_edges<<<NEDGE/256, 256, 0, stream>>>(ei, deg, ebuf);
  k_aggkv<<<NGRAPH*2, 512, 0, stream>>>(deg, ebuf, x, WTk, bk, Kb, WTv, bv, VbT);
  k_attnepi<<<NGRAPH*2, 512, 0, stream>>>(Q, WTq, bq, Kb, VbT, WTo, bo, g0, b0, g1, b1, (float*)d_out);
}

// Round 13
// 70.506 us; speedup vs baseline: 1.2579x; 1.2579x over previous
//
#include <hip/hip_runtime.h>

typedef unsigned int uint32;
typedef unsigned short ushort;
typedef __attribute__((ext_vector_type(8))) short short8;   // 8 bf16 = 4 VGPR
typedef __attribute__((ext_vector_type(4))) float f32x4;

#define NNODES 32768
#define NGRAPH 128
#define PNODES 256
#define SQ 32
#define NEDGE 524288
#define DIM 128
#define NHEAD 4
#define MAXDEG 64     // slots per node (mean 16, ~12 sigma headroom)

__device__ __forceinline__ float u2f(uint32 u){ union{uint32 i; float f;} c; c.i=u; return c.f; }
__device__ __forceinline__ uint32 f2bf(float f){
  union{float f; uint32 i;} c; c.f=f;
  return (c.i + 0x7FFFu + ((c.i>>16)&1u)) >> 16;
}
__device__ __forceinline__ uint32 pk2(float a, float b){ return f2bf(a) | (f2bf(b)<<16); }

// XCD-pair swizzle: 256 blocks, 8 XCDs, both blocks of a graph -> same XCD.
// b = xcd + 8*j (dispatch round-robins xcd = b%8); j in [0,32): g = xcd*16 + j/2.
__device__ __forceinline__ void swz_pair(int b, int& g, int& h){
  const int xcd = b & 7, j = b >> 3;
  g = xcd * 16 + (j >> 1);
  h = j & 1;
}

// ---------------- weight prep (blocks 0-3) + zero deg (blocks 4-35) ----------------
__global__ __launch_bounds__(256) void k_prep0(const float* __restrict__ Wk,
    const float* __restrict__ Wv, const float* __restrict__ Wq, const float* __restrict__ Wo,
    ushort* __restrict__ WTk, ushort* __restrict__ WTv, ushort* __restrict__ WTq,
    ushort* __restrict__ WTo, int4* __restrict__ zbase){
  const int bid = blockIdx.x;
  const int t = threadIdx.x;
  if (bid >= 4){
    int idx = (bid-4)*256 + t;
    if (idx < 8192) zbase[idx] = int4{0,0,0,0};   // deg[32768]
    return;
  }
  __shared__ __align__(16) float Ws2[128*132];
  const float* W = (bid==0) ? Wk : (bid==1) ? Wv : (bid==2) ? Wq : Wo;
  ushort* WT     = (bid==0) ? WTk : (bid==1) ? WTv : (bid==2) ? WTq : WTo;
  for (int idx = t; idx < 4096; idx += 256){
    int k = idx >> 5, c4 = idx & 31;
    *(float4*)&Ws2[k*132 + c4*4] = *(const float4*)&W[k*128 + c4*4];
  }
  __syncthreads();
  for (int idx = t; idx < 2048; idx += 256){
    int n = idx & 127, c8 = idx >> 7;
    uint4 p;
    p.x = pk2(Ws2[(c8*8+0)*132 + n], Ws2[(c8*8+1)*132 + n]);
    p.y = pk2(Ws2[(c8*8+2)*132 + n], Ws2[(c8*8+3)*132 + n]);
    p.z = pk2(Ws2[(c8*8+4)*132 + n], Ws2[(c8*8+5)*132 + n]);
    p.w = pk2(Ws2[(c8*8+6)*132 + n], Ws2[(c8*8+7)*132 + n]);
    *(uint4*)&WT[n*128 + c8*8] = p;
  }
}

// ---------------- edges: deg atomicAdd doubles as slot allocator ----------------
__global__ void k_edges(const int* __restrict__ ei, int* __restrict__ deg,
                        ushort* __restrict__ ebuf){
  int e = blockIdx.x*256 + threadIdx.x;        // grid exact: NEDGE/256
  int s = ei[e];
  int d = ei[NEDGE + e];
  int i = atomicAdd(&deg[d], 1);               // 32768 counters: low contention
  if (i < MAXDEG) ebuf[(d << 6) + i] = (ushort)(s & 255);
}

// ---------------- fused aggregation + K/V GEMM per half-graph ----------------
// K written natural [node][d]; V written TRANSPOSED [graph][d][p] for attnepi.
#define APITCH 132   // u32 per A row (= 264 ushort)
__global__ __launch_bounds__(512) void k_aggkv(
    const int* __restrict__ deg, const ushort* __restrict__ ebuf,
    const float* __restrict__ x,
    const ushort* __restrict__ WTk, const float* __restrict__ bk, ushort* __restrict__ Kb,
    const ushort* __restrict__ WTv, const float* __restrict__ bv, ushort* __restrict__ VbT)
{
  __shared__ __align__(16) char lds[138240];
  uint32* A    = (uint32*)lds;             // [128][132] u32 = bf16 pairs [dst][src]
  ushort* Au   = (ushort*)lds;             // bf16 view
  ushort* xT   = (ushort*)(lds + 67584);   // [128 feat][264 src] bf16
  ushort* xa_s = (ushort*)(lds + 67584);   // [128][136] bf16 (overlays xT after agg)
  ushort* wtA  = (ushort*)(lds + 102400);  // [128][136] bf16 (Wk^T)
  ushort* wtB  = (ushort*)(lds + 0);       // [128][136] bf16 (Wv^T; overlays A)
  ushort* KK   = (ushort*)(lds + 67584);   // K bounce [row][136] (overlays xa_s)
  ushort* VVt  = (ushort*)(lds + 102400);  // V bounce TRANSPOSED [d][136] (overlays wtA)
  float*  dvs  = (float*)(lds + 137216);   // [256]
  const int t = threadIdx.x;
  int g, half;
  swz_pair(blockIdx.x, g, half);           // both halves of a graph on one XCD
  const int base = g*PNODES;
  const int rbase = half*128;

  // P0: dinv slice + zero A (vectorized)
  if (t < 256) dvs[t] = rsqrtf((float)(deg[base + t] + 1));
  {
    uint4* Az = (uint4*)A;
    for (int i = t; i < 4224; i += 512) Az[i] = uint4{0,0,0,0};
  }
  __syncthreads();
  // P1: diagonal (self-loop dn^2) + stage x^T bf16
  if (t < 128){
    float dn = dvs[rbase + t];
    int src = rbase + t;
    uint32 nb = f2bf(dn*dn);
    A[t*APITCH + (src>>1)] = (src & 1) ? (nb<<16) : nb;
  }
  for (int idx = t; idx < 8192; idx += 512){
    int f = idx & 127, s4 = idx >> 7;
    const int r = base + s4*4;
    float v0 = x[(r+0)*DIM + f];
    float v1 = x[(r+1)*DIM + f];
    float v2 = x[(r+2)*DIM + f];
    float v3 = x[(r+3)*DIM + f];
    uint2 p; p.x = pk2(v0, v1); p.y = pk2(v2, v3);
    *(uint2*)&xT[f*264 + s4*4] = p;
  }
  __syncthreads();
  // P2: per-dst slot lists -> A. Cell-ownership by (src>>1)&3 == sub: NO atomics.
  {
    const int r = t >> 2, sub = t & 3;
    const int n = base + rbase + r;
    const int dg = min(deg[n], MAXDEG);
    const float dn = dvs[rbase + r];
    const ushort* eb = ebuf + (n << 6);
    for (int i = 0; i < dg; ++i){
      const int srcl = eb[i];
      if (((srcl >> 1) & 3) != sub) continue;
      const float coef = dn * dvs[srcl];
      uint32* cell = &A[r*APITCH + (srcl>>1)];
      uint32 old = *cell;
      if (srcl & 1){
        float cur = u2f(old & 0xffff0000u);
        *cell = (old & 0xffffu) | (f2bf(cur + coef) << 16);
      } else {
        float cur = u2f(old << 16);
        *cell = (old & 0xffff0000u) | f2bf(cur + coef);
      }
    }
  }
  __syncthreads();
  // P3: xa = A @ x
  const int lane = t & 63, w = t >> 6;
  const int r16 = lane & 15, kg = lane >> 4;
  f32x4 acc[8];
  #pragma unroll
  for (int j = 0; j < 8; ++j) acc[j] = (f32x4){0.f,0.f,0.f,0.f};
  #pragma unroll
  for (int kc = 0; kc < 8; ++kc){
    const short8 a = *(const short8*)&Au[(w*16 + r16)*264 + kc*32 + kg*8];
    #pragma unroll
    for (int ct = 0; ct < 8; ++ct){
      const short8 b = *(const short8*)&xT[(ct*16 + r16)*264 + kc*32 + kg*8];
      acc[ct] = __builtin_amdgcn_mfma_f32_16x16x32_bf16(a, b, acc[ct], 0, 0, 0);
    }
  }
  __syncthreads();
  // P4: xa -> LDS bf16 + stage both weights
  #pragma unroll
  for (int ct = 0; ct < 8; ++ct)
    #pragma unroll
    for (int q = 0; q < 4; ++q)
      xa_s[(w*16 + kg*4 + q)*136 + ct*16 + r16] = (ushort)f2bf(acc[ct][q]);
  for (int idx = t; idx < 2048; idx += 512){
    int n = idx >> 4, c8 = idx & 15;
    *(uint4*)&wtA[n*136 + c8*8] = *(const uint4*)&WTk[n*128 + c8*8];
    *(uint4*)&wtB[n*136 + c8*8] = *(const uint4*)&WTv[n*128 + c8*8];
  }
  __syncthreads();
  // P5: K = xa@Wk + bk ; V = xa@Wv + bv
  f32x4 k0[8], v0[8];
  #pragma unroll
  for (int j = 0; j < 8; ++j){ k0[j] = (f32x4){0.f,0.f,0.f,0.f}; v0[j] = (f32x4){0.f,0.f,0.f,0.f}; }
  #pragma unroll
  for (int kc = 0; kc < 4; ++kc){
    const short8 a = *(const short8*)&xa_s[(w*16 + r16)*136 + kc*32 + kg*8];
    #pragma unroll
    for (int ct = 0; ct < 8; ++ct){
      const short8 b0 = *(const short8*)&wtA[(ct*16 + r16)*136 + kc*32 + kg*8];
      const short8 b1 = *(const short8*)&wtB[(ct*16 + r16)*136 + kc*32 + kg*8];
      k0[ct] = __builtin_amdgcn_mfma_f32_16x16x32_bf16(a, b0, k0[ct], 0, 0, 0);
      v0[ct] = __builtin_amdgcn_mfma_f32_16x16x32_bf16(a, b1, v0[ct], 0, 0, 0);
    }
  }
  __syncthreads();   // all waves done reading xa_s / wtA before bounce overwrite
  #pragma unroll
  for (int ct = 0; ct < 8; ++ct){
    const int col = ct*16 + r16;
    const float bkc = bk[col], bvc = bv[col];
    #pragma unroll
    for (int q = 0; q < 4; ++q){
      const int r = w*16 + kg*4 + q;                 // local row = p
      KK[r*136 + col]  = (ushort)f2bf(k0[ct][q] + bkc);
      VVt[col*136 + r] = (ushort)f2bf(v0[ct][q] + bvc);   // transposed bounce
    }
  }
  __syncthreads();
  // P6: coalesced uint4 stores: K natural, V transposed [g][d][p]
  for (int idx = t; idx < 2048; idx += 512){
    int r = idx >> 4, c8 = idx & 15;
    *(uint4*)&Kb[(base + rbase + r)*DIM + c8*8] = *(const uint4*)&KK[r*136 + c8*8];
  }
  for (int idx = t; idx < 2048; idx += 512){
    int d = idx >> 4, c8 = idx & 15;                 // p-chunk c8*8 within half
    *(uint4*)&VbT[(g*128 + d)*PNODES + rbase + c8*8] = *(const uint4*)&VVt[d*136 + c8*8];
  }
}

// ---------------- fused Q-GEMM + MFMA attention + epilogue (round-11 structure) ----
// 2 blocks/graph (16 queries), 512 threads = 8 waves. All-MFMA; K/Wq/Wo staged in
// LDS; V^T copied straight from pre-transposed global VbT (cheap uint4 copy).
__global__ __launch_bounds__(512) void k_attnepi(
    const float* __restrict__ Qin, const ushort* __restrict__ WTq,
    const float* __restrict__ bq,
    const ushort* __restrict__ Kb, const ushort* __restrict__ VbT,
    const ushort* __restrict__ WoT, const float* __restrict__ bo,
    const float* __restrict__ g0, const float* __restrict__ b0,
    const float* __restrict__ g1, const float* __restrict__ b1,
    float* __restrict__ out)
{
  __shared__ __align__(16) char lds[151040];
  ushort* KbS = (ushort*)lds;             // [256][136] bf16 (69632 B)
  ushort* VT  = (ushort*)lds;             // [128][264] bf16 (67584 B) overlays KbS
  ushort* R2  = (ushort*)(lds + 69632);   // [128][136] bf16: WqT then WoT (34816 B)
  float*  S   = (float*)(lds + 104448);   // [16][264] f32 (16896 B)
  float*  Zf  = (float*)(lds + 104448);   // overlays S
  ushort* Pb  = (ushort*)(lds + 121344);  // [16][264] bf16 (8448 B)
  float*  Yf  = (float*)(lds + 121344);   // [16][132] f32 overlays Pb
  float*  Ob  = (float*)(lds + 129792);   // [16][132] f32 (8448 B)
  float*  Qres= (float*)(lds + 138240);   // [16][132] f32 (8448 B)
  ushort* Qb  = (ushort*)(lds + 146688);  // [16][136] bf16 (4352 B), reused as Yb

  const int t = threadIdx.x;
  const int w = t >> 6, lane = t & 63;
  const int r16 = lane & 15, kg = lane >> 4;
  int g, qh;
  swz_pair(blockIdx.x, g, qh);            // both query-halves of a graph on one XCD
  const int qr0 = g*SQ + qh*16;

  // A: stage K + WqT ; load Q row fragment to regs
  for (int idx = t; idx < 4096; idx += 512){
    int r = idx >> 4, c8 = idx & 15;
    *(uint4*)&KbS[r*136 + c8*8] = *(const uint4*)&Kb[(g*256 + r)*128 + c8*8];
  }
  for (int idx = t; idx < 2048; idx += 512){
    int n = idx >> 4, c8 = idx & 15;
    *(uint4*)&R2[n*136 + c8*8] = *(const uint4*)&WTq[n*128 + c8*8];
  }
  short8 qin[4];
  #pragma unroll
  for (int kc = 0; kc < 4; ++kc){
    const float4 f0 = *(const float4*)&Qin[(qr0 + r16)*128 + kc*32 + kg*8];
    const float4 f1 = *(const float4*)&Qin[(qr0 + r16)*128 + kc*32 + kg*8 + 4];
    union { short8 s; uint32 u[4]; } c;
    c.u[0] = pk2(f0.x, f0.y); c.u[1] = pk2(f0.z, f0.w);
    c.u[2] = pk2(f1.x, f1.y); c.u[3] = pk2(f1.z, f1.w);
    qin[kc] = c.s;
  }
  __syncthreads();

  // A2: Qp tile = Q @ Wq + bq ; wave w owns col tile w
  {
    f32x4 qa = (f32x4){0.f,0.f,0.f,0.f};
    #pragma unroll
    for (int kc = 0; kc < 4; ++kc){
      const short8 bf = *(const short8*)&R2[(w*16 + r16)*136 + kc*32 + kg*8];
      qa = __builtin_amdgcn_mfma_f32_16x16x32_bf16(qin[kc], bf, qa, 0, 0, 0);
    }
    #pragma unroll
    for (int q = 0; q < 4; ++q){
      const int row = kg*4 + q, col = w*16 + r16;
      const float v = qa[q] + bq[col];
      Qres[row*132 + col] = v;
      Qb[row*136 + col] = (ushort)f2bf(v);
    }
  }
  __syncthreads();

  // B: scores S = (Qp·K^T)/sqrt(128); wave w owns key tiles {2w, 2w+1}
  {
    short8 qf[4];
    #pragma unroll
    for (int kc = 0; kc < 4; ++kc)
      qf[kc] = *(const short8*)&Qb[r16*136 + kc*32 + kg*8];
    f32x4 sa[2];
    sa[0] = (f32x4){0.f,0.f,0.f,0.f}; sa[1] = (f32x4){0.f,0.f,0.f,0.f};
    #pragma unroll
    for (int kc = 0; kc < 4; ++kc){
      #pragma unroll
      for (int nt = 0; nt < 2; ++nt){
        const short8 bf = *(const short8*)&KbS[((w*2+nt)*16 + r16)*136 + kc*32 + kg*8];
        sa[nt] = __builtin_amdgcn_mfma_f32_16x16x32_bf16(qf[kc], bf, sa[nt], 0, 0, 0);
      }
    }
    #pragma unroll
    for (int nt = 0; nt < 2; ++nt)
      #pragma unroll
      for (int q = 0; q < 4; ++q)
        S[(kg*4+q)*264 + (w*2+nt)*16 + r16] = sa[nt][q] * 0.08838834764831845f;
  }
  __syncthreads();

  // C: softmax (32 thr/row) -> Pb bf16 ; copy V^T over dead K buffer (uint4)
  {
    const int row = t >> 5, j = t & 31;
    float vals[8];
    float m = -1e30f;
    #pragma unroll
    for (int u = 0; u < 8; ++u){
      vals[u] = S[row*264 + j + 32*u];
      m = fmaxf(m, vals[u]);
    }
    m = fmaxf(m, __shfl_xor(m, 1));
    m = fmaxf(m, __shfl_xor(m, 2));
    m = fmaxf(m, __shfl_xor(m, 4));
    m = fmaxf(m, __shfl_xor(m, 8));
    m = fmaxf(m, __shfl_xor(m, 16));
    float sum = 0.f;
    #pragma unroll
    for (int u = 0; u < 8; ++u){
      vals[u] = __expf(vals[u] - m);
      sum += vals[u];
    }
    sum += __shfl_xor(sum, 1);
    sum += __shfl_xor(sum, 2);
    sum += __shfl_xor(sum, 4);
    sum += __shfl_xor(sum, 8);
    sum += __shfl_xor(sum, 16);
    float inv = 1.f / sum;
    #pragma unroll
    for (int u = 0; u < 8; ++u)
      Pb[row*264 + j + 32*u] = (ushort)f2bf(vals[u] * inv);
  }
  for (int idx = t; idx < 4096; idx += 512){
    int d = idx >> 5, c8 = idx & 31;
    *(uint4*)&VT[d*264 + c8*8] = *(const uint4*)&VbT[(g*128 + d)*PNODES + c8*8];
  }
  __syncthreads();

  // D: O = P·V + Qp residual ; wave w owns d-tile w
  {
    f32x4 oa = (f32x4){0.f,0.f,0.f,0.f};
    #pragma unroll
    for (int kc = 0; kc < 8; ++kc){
      const short8 pa = *(const short8*)&Pb[r16*264 + kc*32 + kg*8];
      const short8 vb = *(const short8*)&VT[(w*16 + r16)*264 + kc*32 + kg*8];
      oa = __builtin_amdgcn_mfma_f32_16x16x32_bf16(pa, vb, oa, 0, 0, 0);
    }
    #pragma unroll
    for (int q = 0; q < 4; ++q){
      const int row = kg*4 + q, col = w*16 + r16;
      Ob[row*132 + col] = oa[q] + Qres[row*132 + col];
    }
  }
  __syncthreads();

  // E: LN0 -> Yf (f32) + Yb (bf16, reuses Qb slot) ; stage WoT into R2
  #pragma unroll
  for (int rr = 0; rr < 2; ++rr){
    const int row = w*2 + rr;
    float x0 = Ob[row*132 + 2*lane], x1 = Ob[row*132 + 2*lane + 1];
    float s = x0 + x1;
    s += __shfl_xor(s,1); s += __shfl_xor(s,2); s += __shfl_xor(s,4);
    s += __shfl_xor(s,8); s += __shfl_xor(s,16); s += __shfl_xor(s,32);
    float mu = s * 0.0078125f;
    float d0 = x0 - mu, d1 = x1 - mu;
    float vv = d0*d0 + d1*d1;
    vv += __shfl_xor(vv,1); vv += __shfl_xor(vv,2); vv += __shfl_xor(vv,4);
    vv += __shfl_xor(vv,8); vv += __shfl_xor(vv,16); vv += __shfl_xor(vv,32);
    float rs = rsqrtf(vv*0.0078125f + 1e-5f);
    const float2 gv = *(const float2*)&g0[2*lane];
    const float2 bv = *(const float2*)&b0[2*lane];
    float y0 = d0*rs*gv.x + bv.x;
    float y1 = d1*rs*gv.y + bv.y;
    Yf[row*132 + 2*lane] = y0; Yf[row*132 + 2*lane + 1] = y1;
    *(uint32*)&Qb[row*136 + 2*lane] = pk2(y0, y1);
  }
  for (int idx = t; idx < 2048; idx += 512){
    int n = idx >> 4, c8 = idx & 15;
    *(uint4*)&R2[n*136 + c8*8] = *(const uint4*)&WoT[n*128 + c8*8];
  }
  __syncthreads();

  // F: Z = Y + relu(Y·Wo + bo) via MFMA ; wave w owns out-col tile w
  {
    f32x4 fa = (f32x4){0.f,0.f,0.f,0.f};
    #pragma unroll
    for (int kc = 0; kc < 4; ++kc){
      const short8 ya = *(const short8*)&Qb[r16*136 + kc*32 + kg*8];
      const short8 wb = *(const short8*)&R2[(w*16 + r16)*136 + kc*32 + kg*8];
      fa = __builtin_amdgcn_mfma_f32_16x16x32_bf16(ya, wb, fa, 0, 0, 0);
    }
    #pragma unroll
    for (int q = 0; q < 4; ++q){
      const int row = kg*4 + q, col = w*16 + r16;
      Zf[row*132 + col] = Yf[row*132 + col] + fmaxf(fa[q] + bo[col], 0.f);
    }
  }
  __syncthreads();

  // G: LN1 -> out
  #pragma unroll
  for (int rr = 0; rr < 2; ++rr){
    const int row = w*2 + rr;
    float z0 = Zf[row*132 + 2*lane], z1 = Zf[row*132 + 2*lane + 1];
    float s = z0 + z1;
    s += __shfl_xor(s,1); s += __shfl_xor(s,2); s += __shfl_xor(s,4);
    s += __shfl_xor(s,8); s += __shfl_xor(s,16); s += __shfl_xor(s,32);
    float mu = s * 0.0078125f;
    float d0 = z0 - mu, d1 = z1 - mu;
    float vv = d0*d0 + d1*d1;
    vv += __shfl_xor(vv,1); vv += __shfl_xor(vv,2); vv += __shfl_xor(vv,4);
    vv += __shfl_xor(vv,8); vv += __shfl_xor(vv,16); vv += __shfl_xor(vv,32);
    float rs = rsqrtf(vv*0.0078125f + 1e-5f);
    const float2 g1v = *(const float2*)&g1[2*lane];
    const float2 b1v = *(const float2*)&b1[2*lane];
    float2 o;
    o.x = d0*rs*g1v.x + b1v.x;
    o.y = d1*rs*g1v.y + b1v.y;
    *(float2*)&out[(qr0 + row)*128 + 2*lane] = o;
  }
}

extern "C" void kernel_launch(void* const* d_in, const int* in_sizes, int n_in,
                              void* d_out, int out_size, void* d_ws, size_t ws_size,
                              hipStream_t stream){
  const float* Q   = (const float*)d_in[0];
  const float* x   = (const float*)d_in[1];
  const int*   ei  = (const int*)d_in[2];
  const float* Wq  = (const float*)d_in[4];
  const float* bq  = (const float*)d_in[5];
  const float* Wk  = (const float*)d_in[6];
  const float* bk  = (const float*)d_in[7];
  const float* Wv  = (const float*)d_in[8];
  const float* bv  = (const float*)d_in[9];
  const float* Wo  = (const float*)d_in[10];
  const float* bo  = (const float*)d_in[11];
  const float* g0  = (const float*)d_in[12];
  const float* b0  = (const float*)d_in[13];
  const float* g1  = (const float*)d_in[14];
  const float* b1  = (const float*)d_in[15];

  char* ws = (char*)d_ws;
  ushort* Kb   = (ushort*)(ws);                  // 8 MB
  ushort* VbT  = (ushort*)(ws + 8388608);        // 8 MB  [g][d][p] transposed V
  ushort* WTk  = (ushort*)(ws + 16777216);       // 32 KB
  ushort* WTv  = (ushort*)(ws + 16809984);       // 32 KB
  ushort* WTq  = (ushort*)(ws + 16842752);       // 32 KB
  ushort* WTo  = (ushort*)(ws + 16875520);       // 32 KB
  int*    deg  = (int*)(ws + 16908288);          // 128 KB
  ushort* ebuf = (ushort*)(ws + 17039360);       // 32768*64*2 = 4 MB

  k_prep0<<<36, 256, 0, stream>>>(Wk, Wv, Wq, Wo, WTk, WTv, WTq, WTo, (int4*)deg);
  k_edges<<<NEDGE/256, 256, 0, stream>>>(ei, deg, ebuf);
  k_aggkv<<<NGRAPH*2, 512, 0, stream>>>(deg, ebuf, x, WTk, bk, Kb, WTv, bv, VbT);
  k_attnepi<<<NGRAPH*2, 512, 0, stream>>>(Q, WTq, bq, Kb, VbT, WTo, bo, g0, b0, g1, b1, (float*)d_out);
}